// Round 3
// baseline (54155.518 us; speedup 1.0000x reference)
//
#include <hip/hip_runtime.h>
#include <hip/hip_bf16.h>
#include <math.h>
#include <string.h>

typedef __hip_bfloat16 bf16;
typedef unsigned short u16;

__device__ __forceinline__ float b2f(u16 u) {
    return __uint_as_float(((unsigned)u) << 16);
}
__device__ __forceinline__ u16 f2b(float f) {
    __hip_bfloat16 h = __float2bfloat16(f);
    return *reinterpret_cast<u16*>(&h);
}
static u16 host_f2b(float f) {
    unsigned u; memcpy(&u, &f, 4);
    u16 hi = (u16)(u >> 16);
    if (u & 0x8000u) hi = (u16)(hi + 1);
    return hi;
}

// typed loaders -------------------------------------------------------------
template<typename T> struct Ld;
template<> struct Ld<u16> {
    static __device__ __forceinline__ float  one(const u16* p) { return b2f(*p); }
    static __device__ __forceinline__ float2 two(const u16* p) {
        ushort2 u = *(const ushort2*)p; return make_float2(b2f(u.x), b2f(u.y));
    }
};
template<> struct Ld<float> {
    static __device__ __forceinline__ float  one(const float* p) { return *p; }
    static __device__ __forceinline__ float2 two(const float* p) { return *(const float2*)p; }
};

#define FLAG_INIT 0x7FFFFFFFu

// flags[0]=bf16-pipe phase flag, flags[1]=fp32-pipe phase flag, flags[2]=dtype (0=bf16,1=fp32)
__global__ void init_flags(unsigned* f) { f[0] = FLAG_INIT; f[1] = FLAG_INIT; f[2] = 0u; }

__global__ __launch_bounds__(256) void sniff_dtype(const u16* __restrict__ x, unsigned* dflag) {
    int cnt = 0;
    for (int i = threadIdx.x; i < 8192; i += 256) {
        unsigned e = (x[i] >> 7) & 0xFFu;
        if (e >= 100u && e <= 140u) cnt++;
    }
    __shared__ int red[256];
    red[threadIdx.x] = cnt; __syncthreads();
    for (int s = 128; s; s >>= 1) {
        if (threadIdx.x < s) red[threadIdx.x] += red[threadIdx.x + s];
        __syncthreads();
    }
    if (threadIdx.x == 0) *dflag = (red[0] < 7373) ? 1u : 0u;   // <90% sane bf16 words -> fp32
}

__global__ __launch_bounds__(256) void check_f32(const float* __restrict__ p, size_t n,
                                                 unsigned phase, unsigned* flag) {
    size_t i = (size_t)blockIdx.x * blockDim.x + threadIdx.x;
    size_t stride = (size_t)gridDim.x * blockDim.x;
    bool bad = false;
    for (; i < n; i += stride) { float v = p[i]; if (!__builtin_isfinite(v)) bad = true; }
    if (bad) atomicMin(flag, phase);
}
__global__ __launch_bounds__(256) void check_bf16(const u16* __restrict__ p, size_t n,
                                                  unsigned phase, unsigned* flag) {
    size_t i = (size_t)blockIdx.x * blockDim.x + threadIdx.x;
    size_t stride = (size_t)gridDim.x * blockDim.x;
    bool bad = false;
    for (; i < n; i += stride) { float v = b2f(p[i]); if (!__builtin_isfinite(v)) bad = true; }
    if (bad) atomicMin(flag, phase);
}

__global__ __launch_bounds__(256) void select_out(
    const float* __restrict__ res_bf, const float* __restrict__ res_fp,
    const unsigned* __restrict__ flags, void* out, size_t n)
{
    unsigned d = flags[2];
    const float* res = d ? res_fp : res_bf;
    unsigned f = d ? flags[1] : flags[0];
    size_t i = (size_t)blockIdx.x * blockDim.x + threadIdx.x;
    size_t stride = (size_t)gridDim.x * blockDim.x;
    for (; i < n; i += stride) {
        float v = res[i];
        if (f != FLAG_INIT) v = 100.0f * (float)(f + 1u) + (d ? 5000.0f : 0.0f);
        if (!__builtin_isfinite(v)) v = 99999.0f;
        if (d) ((float*)out)[i] = v;
        else   ((u16*)out)[i] = f2b(v);
    }
}

__global__ __launch_bounds__(256) void ws_sentinel(u16* out, size_t n, u16 pat) {
    size_t i = (size_t)blockIdx.x * blockDim.x + threadIdx.x;
    size_t stride = (size_t)gridDim.x * blockDim.x;
    for (; i < n; i += stride) out[i] = pat;
}

// ---------------------------------------------------------------------------
// GEMM: acc = A[M,K] @ W[K,N(ldw)] (+bias if non-null)
//   resid != nullptr: resid[m,n] = beta*resid[m,n] + rs*(acc+bias)  (fp32, stride N)
//   resid == nullptr: C[m,n] = bf16(acc+bias)
// 64x64 tile, 256 threads, 4x4/thread, K-tile 16, fp32 accumulate.
// ---------------------------------------------------------------------------
template<typename TA, typename TW>
__global__ __launch_bounds__(256) void gemm_bias(
    const TA* __restrict__ A, const TW* __restrict__ W,
    const TW* __restrict__ bias, u16* __restrict__ C,
    float* __restrict__ resid, int M, int N, int K, int ldw, float rs, float beta)
{
    __shared__ float As[16][68];
    __shared__ float Ws[16][68];
    int tid = threadIdx.x;
    int tx = tid & 15, ty = tid >> 4;
    int n0 = blockIdx.x * 64, m0 = blockIdx.y * 64;
    float acc[4][4] = {};

    for (int k0 = 0; k0 < K; k0 += 16) {
        #pragma unroll
        for (int i = 0; i < 2; ++i) {            // A tile: 64m x 16k
            int e = tid + i * 256;
            int r = e >> 3, c2 = (e & 7) << 1;
            int mm = m0 + r, kk = k0 + c2;
            float v0 = 0.f, v1 = 0.f;
            if (mm < M) {
                if (kk + 1 < K) { float2 u = Ld<TA>::two(A + (size_t)mm * K + kk); v0 = u.x; v1 = u.y; }
                else if (kk < K) { v0 = Ld<TA>::one(A + (size_t)mm * K + kk); }
            }
            As[c2][r] = v0; As[c2 + 1][r] = v1;
        }
        #pragma unroll
        for (int i = 0; i < 2; ++i) {            // W tile: 16k x 64n
            int e = tid + i * 256;
            int r = e >> 5, c2 = (e & 31) << 1;
            int kk = k0 + r, nn = n0 + c2;
            float v0 = 0.f, v1 = 0.f;
            if (kk < K) {
                if (nn + 1 < N) { float2 u = Ld<TW>::two(W + (size_t)kk * ldw + nn); v0 = u.x; v1 = u.y; }
                else if (nn < N) { v0 = Ld<TW>::one(W + (size_t)kk * ldw + nn); }
            }
            Ws[r][c2] = v0; Ws[r][c2 + 1] = v1;
        }
        __syncthreads();
        #pragma unroll
        for (int kk = 0; kk < 16; ++kk) {
            float4 av = *(const float4*)&As[kk][ty << 2];
            float4 bv = *(const float4*)&Ws[kk][tx << 2];
            float a[4] = {av.x, av.y, av.z, av.w};
            float b[4] = {bv.x, bv.y, bv.z, bv.w};
            #pragma unroll
            for (int i = 0; i < 4; ++i)
                #pragma unroll
                for (int j = 0; j < 4; ++j)
                    acc[i][j] += a[i] * b[j];
        }
        __syncthreads();
    }

    float bvals[4];
    #pragma unroll
    for (int j = 0; j < 4; ++j) {
        int n = n0 + (tx << 2) + j;
        bvals[j] = (bias != nullptr && n < N) ? Ld<TW>::one(bias + n) : 0.f;
    }

    if (resid) {   // full tiles, N multiple of 4 in all resid uses
        #pragma unroll
        for (int i = 0; i < 4; ++i) {
            int m = m0 + (ty << 2) + i;
            if (m >= M) continue;
            size_t off = (size_t)m * N + n0 + (tx << 2);
            float4 prev = make_float4(0.f, 0.f, 0.f, 0.f);
            if (beta != 0.f) prev = *(const float4*)(resid + off);
            float4 o;
            o.x = prev.x * beta + (acc[i][0] + bvals[0]) * rs;
            o.y = prev.y * beta + (acc[i][1] + bvals[1]) * rs;
            o.z = prev.z * beta + (acc[i][2] + bvals[2]) * rs;
            o.w = prev.w * beta + (acc[i][3] + bvals[3]) * rs;
            *(float4*)(resid + off) = o;
        }
    } else if (((N & 3) == 0) && (n0 + 64 <= N)) {
        #pragma unroll
        for (int i = 0; i < 4; ++i) {
            int m = m0 + (ty << 2) + i;
            if (m >= M) continue;
            ushort4 pk;
            pk.x = f2b(acc[i][0] + bvals[0]);
            pk.y = f2b(acc[i][1] + bvals[1]);
            pk.z = f2b(acc[i][2] + bvals[2]);
            pk.w = f2b(acc[i][3] + bvals[3]);
            *(ushort4*)(C + (size_t)m * N + n0 + (tx << 2)) = pk;
        }
    } else {
        #pragma unroll
        for (int i = 0; i < 4; ++i) {
            int m = m0 + (ty << 2) + i;
            if (m >= M) continue;
            #pragma unroll
            for (int j = 0; j < 4; ++j) {
                int n = n0 + (tx << 2) + j;
                if (n < N) C[(size_t)m * N + n] = f2b(acc[i][j] + bvals[j]);
            }
        }
    }
}

// ---------------------------------------------------------------------------
// Fused SwiGLU gate GEMM: C[M,N] = silu(A@W1+b1) * (A@W3+b3); A is ws bf16.
// ---------------------------------------------------------------------------
template<typename TW>
__global__ __launch_bounds__(256) void gemm_gate(
    const u16* __restrict__ A, const TW* __restrict__ W1, const TW* __restrict__ B1,
    const TW* __restrict__ W3, const TW* __restrict__ B3, u16* __restrict__ C,
    int M, int N, int K, int ldw)
{
    __shared__ float As[16][68];
    __shared__ float W1s[16][68];
    __shared__ float W3s[16][68];
    int tid = threadIdx.x;
    int tx = tid & 15, ty = tid >> 4;
    int n0 = blockIdx.x * 64, m0 = blockIdx.y * 64;
    float acc1[4][4] = {}, acc3[4][4] = {};

    for (int k0 = 0; k0 < K; k0 += 16) {
        #pragma unroll
        for (int i = 0; i < 2; ++i) {
            int e = tid + i * 256;
            int r = e >> 3, c2 = (e & 7) << 1;
            int mm = m0 + r, kk = k0 + c2;
            float v0 = 0.f, v1 = 0.f;
            if (mm < M && kk + 1 < K) { float2 u = Ld<u16>::two(A + (size_t)mm * K + kk); v0 = u.x; v1 = u.y; }
            As[c2][r] = v0; As[c2 + 1][r] = v1;
        }
        #pragma unroll
        for (int i = 0; i < 2; ++i) {
            int e = tid + i * 256;
            int r = e >> 5, c2 = (e & 31) << 1;
            int kk = k0 + r, nn = n0 + c2;
            float a0 = 0.f, a1 = 0.f, c0 = 0.f, c1 = 0.f;
            if (kk < K && nn + 1 < N) {
                float2 u = Ld<TW>::two(W1 + (size_t)kk * ldw + nn); a0 = u.x; a1 = u.y;
                float2 w = Ld<TW>::two(W3 + (size_t)kk * ldw + nn); c0 = w.x; c1 = w.y;
            }
            W1s[r][c2] = a0; W1s[r][c2 + 1] = a1;
            W3s[r][c2] = c0; W3s[r][c2 + 1] = c1;
        }
        __syncthreads();
        #pragma unroll
        for (int kk = 0; kk < 16; ++kk) {
            float4 av = *(const float4*)&As[kk][ty << 2];
            float4 b1v = *(const float4*)&W1s[kk][tx << 2];
            float4 b3v = *(const float4*)&W3s[kk][tx << 2];
            float a[4] = {av.x, av.y, av.z, av.w};
            float b1a[4] = {b1v.x, b1v.y, b1v.z, b1v.w};
            float b3a[4] = {b3v.x, b3v.y, b3v.z, b3v.w};
            #pragma unroll
            for (int i = 0; i < 4; ++i)
                #pragma unroll
                for (int j = 0; j < 4; ++j) {
                    acc1[i][j] += a[i] * b1a[j];
                    acc3[i][j] += a[i] * b3a[j];
                }
        }
        __syncthreads();
    }

    #pragma unroll
    for (int i = 0; i < 4; ++i) {
        int m = m0 + (ty << 2) + i;
        if (m >= M) continue;
        #pragma unroll
        for (int j = 0; j < 4; ++j) {
            int n = n0 + (tx << 2) + j;
            if (n >= N) continue;
            float u1 = acc1[i][j] + Ld<TW>::one(B1 + n);
            float u3 = acc3[i][j] + Ld<TW>::one(B3 + n);
            float s = u1 / (1.f + expf(-u1));
            C[(size_t)m * N + n] = f2b(s * u3);
        }
    }
}

// ---------------------------------------------------------------------------
// RMSNorm over last dim (1024)
// ---------------------------------------------------------------------------
template<typename TW>
__global__ __launch_bounds__(256) void rmsnorm_k(
    const float* __restrict__ h, const TW* __restrict__ w, u16* __restrict__ g)
{
    const int N = 1024;
    size_t row = blockIdx.x;
    const float* hr = h + row * N;
    float vals[4];
    float ss = 0.f;
    #pragma unroll
    for (int i = 0; i < 4; ++i) {
        vals[i] = hr[threadIdx.x + i * 256];
        ss += vals[i] * vals[i];
    }
    #pragma unroll
    for (int off = 32; off; off >>= 1) ss += __shfl_down(ss, off, 64);
    __shared__ float red[4];
    int wid = threadIdx.x >> 6, lane = threadIdx.x & 63;
    if (lane == 0) red[wid] = ss;
    __syncthreads();
    float tot = red[0] + red[1] + red[2] + red[3];
    float scale = rsqrtf(tot * (1.f / 1024.f) + 1e-6f);
    #pragma unroll
    for (int i = 0; i < 4; ++i) {
        int c = threadIdx.x + i * 256;
        g[row * N + c] = f2b(vals[i] * scale * Ld<TW>::one(w + c));
    }
}

// ---------------------------------------------------------------------------
// RoPE, self-contained per thread (pairs (j, j+32) within a head). In-place.
// ---------------------------------------------------------------------------
__global__ __launch_bounds__(256) void rope_k(u16* __restrict__ q, u16* __restrict__ kbuf)
{
    u16* p = (blockIdx.y == 0 ? q : kbuf) + (size_t)blockIdx.x * 1024;
    int s = blockIdx.x & 511;
    #pragma unroll
    for (int i = 0; i < 2; ++i) {
        int pidx = threadIdx.x + i * 256;
        int head = pidx >> 5;
        int j = pidx & 31;
        int c1 = head * 64 + j;
        int c2 = c1 + 32;
        float inv = powf(10000.f, -(float)j * (1.f / 32.f));
        float ang = (float)s * inv;
        float cs = cosf(ang), sn = sinf(ang);
        float x1 = b2f(p[c1]);
        float x2 = b2f(p[c2]);
        p[c1] = f2b(x1 * cs - x2 * sn);
        p[c2] = f2b(x2 * cs + x1 * sn);
    }
}

// ---------------------------------------------------------------------------
// Attention: softmax(q k^T / 8) v per (b, head). One wave per q-row.
// ---------------------------------------------------------------------------
__global__ __launch_bounds__(256) void attn_k(
    const u16* __restrict__ q, const u16* __restrict__ k,
    const u16* __restrict__ v, u16* __restrict__ o)
{
    int wid = threadIdx.x >> 6, lane = threadIdx.x & 63;
    int idx = blockIdx.x * 4 + wid;
    int sq = idx & 511;
    int bh = idx >> 9;
    int hh = bh & 15;
    int b  = bh >> 4;
    size_t tokrow = (size_t)b * 512 + sq;
    const u16* qr = q + tokrow * 1024 + hh * 64;
    const u16* kb = k + (size_t)b * 512 * 1024 + hh * 64;
    const u16* vb = v + (size_t)b * 512 * 1024 + hh * 64;

    __shared__ float qs[4][64];
    __shared__ float ps[4][512];
    qs[wid][lane] = b2f(qr[lane]);
    __syncthreads();

    float sc[8];
    #pragma unroll
    for (int jj = 0; jj < 8; ++jj) {
        int j = jj * 64 + lane;
        const ushort2* kr = (const ushort2*)(kb + (size_t)j * 1024);
        float s = 0.f;
        #pragma unroll
        for (int d2 = 0; d2 < 32; ++d2) {
            ushort2 u = kr[d2];
            s += qs[wid][d2 * 2] * b2f(u.x) + qs[wid][d2 * 2 + 1] * b2f(u.y);
        }
        sc[jj] = s * 0.125f;
    }
    float m = sc[0];
    #pragma unroll
    for (int jj = 1; jj < 8; ++jj) m = fmaxf(m, sc[jj]);
    #pragma unroll
    for (int off = 32; off; off >>= 1) m = fmaxf(m, __shfl_xor(m, off, 64));
    float l = 0.f;
    #pragma unroll
    for (int jj = 0; jj < 8; ++jj) {
        float p = expf(sc[jj] - m);
        l += p;
        ps[wid][jj * 64 + lane] = p;
    }
    #pragma unroll
    for (int off = 32; off; off >>= 1) l += __shfl_xor(l, off, 64);
    __syncthreads();

    float acc = 0.f;
    for (int j = 0; j < 512; ++j) {
        acc += ps[wid][j] * b2f(vb[(size_t)j * 1024 + lane]);
    }
    o[tokrow * 1024 + hh * 64 + lane] = f2b(acc / l);
}

// ---------------------------------------------------------------------------
// One full forward pass viewed with input scalar type T; result -> res (fp32).
// ---------------------------------------------------------------------------
template<typename T>
static void run_pipe(void* const* d_in, char* ws, float* res, unsigned* flag,
                     bool big, hipStream_t stream)
{
    const T* x      = (const T*)d_in[0];
    const T* in_w   = (const T*)d_in[1];
    const T* in_b   = (const T*)d_in[2];
    const T* norm1w = (const T*)d_in[3];
    const T* norm2w = (const T*)d_in[4];
    const T* wq     = (const T*)d_in[5];
    const T* bq     = (const T*)d_in[6];
    const T* wk     = (const T*)d_in[7];
    const T* bk     = (const T*)d_in[8];
    const T* wv     = (const T*)d_in[9];
    const T* bv     = (const T*)d_in[10];
    const T* wo     = (const T*)d_in[11];
    const T* bo     = (const T*)d_in[12];
    const T* w1     = (const T*)d_in[13];
    const T* b1     = (const T*)d_in[14];
    const T* w3     = (const T*)d_in[15];
    const T* b3     = (const T*)d_in[16];
    const T* w2     = (const T*)d_in[17];
    const T* b2     = (const T*)d_in[18];
    const T* onormw = (const T*)d_in[19];
    const T* out_w  = (const T*)d_in[20];
    const T* out_b  = (const T*)d_in[21];

    const int M = 8192, H = 1024, A = 2730;
    const float RS = 0.4082482904638631f;
    const size_t OFF = 256;

    float* h = (float*)(ws + OFF);                  // 32 MiB
    u16*   g = (u16*)(ws + OFF + 33554432ull);      // 16 MiB

    dim3 blk(256);
    dim3 cgrid(1024);

    gemm_bias<T, T><<<dim3(16, 128), blk, 0, stream>>>(x, in_w, in_b, (u16*)nullptr, h, M, H, 128, H, 1.0f, 0.0f);
    check_f32<<<cgrid, blk, 0, stream>>>(h, (size_t)M * H, 0u, flag);

    if (big) {
        u16* q  = (u16*)(ws + OFF + 50331648ull);
        u16* k  = (u16*)(ws + OFF + 67108864ull);
        u16* v  = (u16*)(ws + OFF + 83886080ull);
        u16* ff = q;   // 8192*2730 bf16 = 42.7 MiB aliases dead q/k/v

        for (int l = 0; l < 6; ++l) {
            rmsnorm_k<T><<<8192, blk, 0, stream>>>(h, norm1w + l * H, g);
            if (l == 0) check_bf16<<<cgrid, blk, 0, stream>>>(g, (size_t)M * H, 1u, flag);
            gemm_bias<u16, T><<<dim3(16, 128), blk, 0, stream>>>(g, wq + (size_t)l * H * H, bq + l * H, q, (float*)nullptr, M, H, H, H, 0.f, 0.f);
            gemm_bias<u16, T><<<dim3(16, 128), blk, 0, stream>>>(g, wk + (size_t)l * H * H, bk + l * H, k, (float*)nullptr, M, H, H, H, 0.f, 0.f);
            gemm_bias<u16, T><<<dim3(16, 128), blk, 0, stream>>>(g, wv + (size_t)l * H * H, bv + l * H, v, (float*)nullptr, M, H, H, H, 0.f, 0.f);
            rope_k<<<dim3(8192, 2), blk, 0, stream>>>(q, k);
            if (l == 0) {
                check_bf16<<<cgrid, blk, 0, stream>>>(q, (size_t)M * H, 2u, flag);
                check_bf16<<<cgrid, blk, 0, stream>>>(k, (size_t)M * H, 3u, flag);
                check_bf16<<<cgrid, blk, 0, stream>>>(v, (size_t)M * H, 4u, flag);
            }
            attn_k<<<32768, blk, 0, stream>>>(q, k, v, g);
            if (l == 0) check_bf16<<<cgrid, blk, 0, stream>>>(g, (size_t)M * H, 5u, flag);
            gemm_bias<u16, T><<<dim3(16, 128), blk, 0, stream>>>(g, wo + (size_t)l * H * H, bo + l * H, (u16*)nullptr, h, M, H, H, H, RS, 1.0f);
            if (l == 0) check_f32<<<cgrid, blk, 0, stream>>>(h, (size_t)M * H, 6u, flag);
            rmsnorm_k<T><<<8192, blk, 0, stream>>>(h, norm2w + l * H, g);
            if (l == 0) check_bf16<<<cgrid, blk, 0, stream>>>(g, (size_t)M * H, 7u, flag);
            gemm_gate<T><<<dim3(43, 128), blk, 0, stream>>>(g, w1 + (size_t)l * H * A, b1 + (size_t)l * A,
                                                            w3 + (size_t)l * H * A, b3 + (size_t)l * A, ff, M, A, H, A);
            if (l == 0) check_bf16<<<cgrid, blk, 0, stream>>>(ff, (size_t)M * A, 8u, flag);
            gemm_bias<u16, T><<<dim3(16, 128), blk, 0, stream>>>(ff, w2 + (size_t)l * A * H, b2 + l * H, (u16*)nullptr, h, M, H, A, H, RS, 1.0f);
            check_f32<<<cgrid, blk, 0, stream>>>(h, (size_t)M * H, 9u + (unsigned)l, flag);
        }
    } else {
        u16* qs = (u16*)(ws + OFF + 50331648ull);
        u16* ks = (u16*)(ws + OFF + 51380224ull);
        u16* vs = (u16*)(ws + OFF + 52428800ull);
        u16* ff = (u16*)(ws + OFF + 53477376ull);
        const int NC = 546;

        for (int l = 0; l < 6; ++l) {
            rmsnorm_k<T><<<8192, blk, 0, stream>>>(h, norm1w + l * H, g);
            if (l == 0) check_bf16<<<cgrid, blk, 0, stream>>>(g, (size_t)M * H, 1u, flag);
            for (int b = 0; b < 16; ++b) {
                const u16* gsl = g + (size_t)b * 512 * H;
                gemm_bias<u16, T><<<dim3(16, 8), blk, 0, stream>>>(gsl, wq + (size_t)l * H * H, bq + l * H, qs, (float*)nullptr, 512, H, H, H, 0.f, 0.f);
                gemm_bias<u16, T><<<dim3(16, 8), blk, 0, stream>>>(gsl, wk + (size_t)l * H * H, bk + l * H, ks, (float*)nullptr, 512, H, H, H, 0.f, 0.f);
                gemm_bias<u16, T><<<dim3(16, 8), blk, 0, stream>>>(gsl, wv + (size_t)l * H * H, bv + l * H, vs, (float*)nullptr, 512, H, H, H, 0.f, 0.f);
                rope_k<<<dim3(512, 2), blk, 0, stream>>>(qs, ks);
                if (l == 0 && b == 0) {
                    check_bf16<<<cgrid, blk, 0, stream>>>(qs, (size_t)512 * H, 2u, flag);
                    check_bf16<<<cgrid, blk, 0, stream>>>(ks, (size_t)512 * H, 3u, flag);
                    check_bf16<<<cgrid, blk, 0, stream>>>(vs, (size_t)512 * H, 4u, flag);
                }
                attn_k<<<2048, blk, 0, stream>>>(qs, ks, vs, g + (size_t)b * 512 * H);
                if (l == 0 && b == 0) check_bf16<<<cgrid, blk, 0, stream>>>(g, (size_t)512 * H, 5u, flag);
                gemm_bias<u16, T><<<dim3(16, 8), blk, 0, stream>>>(g + (size_t)b * 512 * H, wo + (size_t)l * H * H, bo + l * H,
                                                                   (u16*)nullptr, h + (size_t)b * 512 * H, 512, H, H, H, RS, 1.0f);
            }
            if (l == 0) check_f32<<<cgrid, blk, 0, stream>>>(h, (size_t)M * H, 6u, flag);
            rmsnorm_k<T><<<8192, blk, 0, stream>>>(h, norm2w + l * H, g);
            if (l == 0) check_bf16<<<cgrid, blk, 0, stream>>>(g, (size_t)M * H, 7u, flag);
            for (int c = 0; c < 5; ++c) {
                int noff = c * NC;
                gemm_gate<T><<<dim3(9, 128), blk, 0, stream>>>(g, w1 + (size_t)l * H * A + noff, b1 + (size_t)l * A + noff,
                                                               w3 + (size_t)l * H * A + noff, b3 + (size_t)l * A + noff,
                                                               ff, M, NC, H, A);
                if (l == 0 && c == 0) check_bf16<<<cgrid, blk, 0, stream>>>(ff, (size_t)M * NC, 8u, flag);
                gemm_bias<u16, T><<<dim3(16, 128), blk, 0, stream>>>(ff, w2 + (size_t)l * A * H + (size_t)noff * H,
                                                                     (c == 0) ? (b2 + l * H) : (const T*)nullptr,
                                                                     (u16*)nullptr, h, M, H, NC, H, RS, 1.0f);
            }
            check_f32<<<cgrid, blk, 0, stream>>>(h, (size_t)M * H, 9u + (unsigned)l, flag);
        }
    }

    rmsnorm_k<T><<<8192, blk, 0, stream>>>(h, onormw, g);
    check_bf16<<<cgrid, blk, 0, stream>>>(g, (size_t)M * H, 15u, flag);
    gemm_bias<u16, T><<<dim3(2, 128), blk, 0, stream>>>(g, out_w, out_b, (u16*)nullptr, res, M, 128, H, 128, 1.0f, 0.0f);
    check_f32<<<cgrid, blk, 0, stream>>>(res, (size_t)M * 128, 16u, flag);
}

// ---------------------------------------------------------------------------
extern "C" void kernel_launch(void* const* d_in, const int* in_sizes, int n_in,
                              void* d_out, int out_size, void* d_ws, size_t ws_size,
                              hipStream_t stream)
{
    const size_t OFF = 256;
    const size_t BIG_END = 100663296ull;   // h+g+q+k+v
    const size_t CMP_END = 62423040ull;    // h+g+qs+ks+vs+ff
    const size_t RES = 4194304ull;         // 8192*128 fp32
    const size_t BIG_NEED = OFF + BIG_END + 2 * RES;
    const size_t CMP_NEED = OFF + CMP_END + 2 * RES;

    char* ws = (char*)d_ws;
    unsigned* flags = (unsigned*)ws;
    size_t n = (size_t)out_size;
    dim3 blk(256);

    if (ws_size >= CMP_NEED) {
        bool big = (ws_size >= BIG_NEED);
        size_t end = big ? BIG_END : CMP_END;
        float* res_bf = (float*)(ws + OFF + end);
        float* res_fp = (float*)(ws + OFF + end + RES);
        init_flags<<<1, 1, 0, stream>>>(flags);
        sniff_dtype<<<1, 256, 0, stream>>>((const u16*)d_in[0], flags + 2);
        run_pipe<u16>(d_in, ws, res_bf, flags + 0, big, stream);
        run_pipe<float>(d_in, ws, res_fp, flags + 1, big, stream);
        select_out<<<1024, blk, 0, stream>>>(res_bf, res_fp, flags, d_out, n);
    } else {
        float v = 3000.0f + (float)(ws_size >> 20);
        ws_sentinel<<<1024, blk, 0, stream>>>((u16*)d_out, n, host_f2b(v));
    }
}